// Round 9
// baseline (389.255 us; speedup 1.0000x reference)
//
#include <hip/hip_runtime.h>

// MHA forward: x@Wq^T/Wk^T/Wv^T -> RoPE(q,k) -> softmax(qk^T/sqrt(hd))v -> @Wo^T
// B=2 H=16 S=2048 D=2048 HD=128. bf16 MFMA, fp32 accum.
// R14: best-measured config = SPLIT projections with v LAST (R12, 363us;
// merged R13 = 382us -- Vt evicted from L2 by Q/K writes before attn reads).
// Changes vs R12: (1) qk switched from my 8-phase port (768 TF, 89.5us) to
// the measured-904TF 2-phase 128^2 structure restricted to N=4096 (grid
// 32x32 = exactly one 4/CU round, ~76us predicted); (2) attn K/V
// double-buffered (R9's verified pattern): prefetch iter+1 at iter top,
// one vmcnt(0)+barrier at iter end. v-kernel unchanged and kept last.

#define DIMN 2048
#define SEQ  2048
#define NH   16
#define HDIM 128
#define NB   2
#define TOK  (NB*SEQ)          // 4096
#define QSCALE 0.08838834764831845f

typedef __attribute__((ext_vector_type(8)))  short bf16x8;
typedef __attribute__((ext_vector_type(4)))  float f32x4;
typedef __attribute__((ext_vector_type(16))) float f32x16;

__device__ __forceinline__ short f2bf(float f) {
  union { float f; unsigned u; } v; v.f = f;
  unsigned r = v.u + 0x7FFFu + ((v.u >> 16) & 1u);   // RNE
  return (short)(r >> 16);
}
__device__ __forceinline__ float bf2f(short b) {
  union { unsigned u; float f; } v; v.u = ((unsigned)(unsigned short)b) << 16;
  return v.f;
}
__device__ __forceinline__ unsigned packbf(float a, float b) {  // RNE pack
  union { float f; unsigned u; } x, y; x.f = a; y.f = b;
  unsigned ua = x.u + 0x7FFFu + ((x.u >> 16) & 1u);
  unsigned ub = y.u + 0x7FFFu + ((y.u >> 16) & 1u);
  return (ua >> 16) | (ub & 0xFFFF0000u);
}
__device__ __forceinline__ void async16(const void* g, void* l) {
  __builtin_amdgcn_global_load_lds(
      (const __attribute__((address_space(1))) unsigned*)g,
      (__attribute__((address_space(3))) unsigned*)l, 16, 0, 0);
}
// per-wave dtype detect from first 1KB of x: 1 = bf16 inputs
__device__ __forceinline__ int detect_bf16(const unsigned* x32) {
  const int lane = threadIdx.x & 63;
  int cnt = 0;
#pragma unroll
  for (int i = 0; i < 4; ++i) {
    unsigned w = x32[lane * 4 + i];
    unsigned e = (w >> 7) & 0xFFu;
    cnt += (e >= 90u && e <= 160u) ? 1 : 0;
  }
#pragma unroll
  for (int o = 1; o < 64; o <<= 1) cnt += __shfl_xor(cnt, o);
  return cnt > 180;
}

// ---- convert x + 4 weights (+freqs); copy blocks are no-ops in bf16 mode ----
__global__ void k_cvt_fused(const void* __restrict__ x,  const void* __restrict__ wq,
                            const void* __restrict__ wk, const void* __restrict__ wv,
                            const void* __restrict__ wo,
                            const void* __restrict__ cfr, const void* __restrict__ sfr,
                            unsigned long long* __restrict__ Xb,
                            unsigned long long* __restrict__ Wqkv,
                            unsigned long long* __restrict__ Wo,
                            float* __restrict__ fc, float* __restrict__ fs,
                            int* __restrict__ flagout) {
  const int fl = detect_bf16((const unsigned*)x);
  const int blk = blockIdx.x;
  if (blk == 0 && threadIdx.x == 0) *flagout = fl;
  if (blk >= 24576) {                       // freqs: fp32 outputs (always)
    const int fb = blk - 24576;
    const void* src = (fb < 512) ? cfr : sfr;
    float* dst = (fb < 512) ? fc : fs;
    const int i = (fb & 511) * 256 + threadIdx.x;
    dst[i] = fl ? bf2f(((const short*)src)[i]) : ((const float*)src)[i];
    return;
  }
  if (fl) return;                           // bf16 inputs: GEMMs read d_in directly
  const void* src; unsigned long long* dst; int base;
  if      (blk <  8192) { src = x;  dst = Xb;             base = blk;          }
  else if (blk < 12288) { src = wq; dst = Wqkv;           base = blk - 8192;   }
  else if (blk < 16384) { src = wk; dst = Wqkv + 1048576; base = blk - 12288;  }
  else if (blk < 20480) { src = wv; dst = Wqkv + 2097152; base = blk - 16384;  }
  else                  { src = wo; dst = Wo;             base = blk - 20480;  }
  const int i = base * 256 + threadIdx.x;
  float4 v = ((const float4*)src)[i];
  dst[i] = (unsigned long long)(unsigned)packbf(v.x, v.y)
         | ((unsigned long long)(unsigned)packbf(v.z, v.w) << 32);
}

// ---- Q+K GEMM: C[M=4096, N=4096] = X @ [Wq;Wk]^T, 2-phase 128^2 ----
// The 904-TF-measured merged-qkv kernel restricted to the Q/K region.
// Grid 32x32 = 1024 blocks = exactly one round at 4 blocks/CU.
// Epilogue: wave-private LDS bounce + fused RoPE (Q scaled by QSCALE).
__global__ __launch_bounds__(256, 4)
void k_gemm_qk2(const void* __restrict__ xraw, const short* __restrict__ Xb,
                const void* __restrict__ wqraw, const void* __restrict__ wkraw,
                const short* __restrict__ Wcvt,
                short* __restrict__ Qb, short* __restrict__ Kb,
                const float* __restrict__ fc, const float* __restrict__ fs,
                const int* __restrict__ flagp) {
  __shared__ short As[128 * 64];
  __shared__ short Bs[128 * 64];
  const int tid = threadIdx.x, lane = tid & 63, wv = tid >> 6;
  const int lo = lane & 15, hi = lane >> 4;
  const int m_base = blockIdx.y * 128, n_base = blockIdx.x * 128;
  const int m0w = (wv >> 1) * 64, n0w = (wv & 1) * 64;
  const int rr = lane >> 3;
  const int gsw = (lane & 7) ^ (rr & 7);
  const int proj = n_base >> 11;              // 0=Q 1=K
  const int nloc = n_base & 2047;

  const int fl = *flagp;
  const short* Ap = fl ? (const short*)xraw : Xb;
  const short* Wp = fl ? (const short*)((proj == 0) ? wqraw : wkraw)
                       : (Wcvt + (size_t)proj * 4194304);

  f32x4 acc[4][4];
#pragma unroll
  for (int i = 0; i < 4; i++)
#pragma unroll
    for (int j = 0; j < 4; j++) acc[i][j] = (f32x4)0.0f;

  for (int k0 = 0; k0 < DIMN; k0 += 64) {
#pragma unroll
    for (int i = 0; i < 4; ++i) {
      const int c = wv * 4 + i;
      const int row = c * 8 + rr;
      async16(Ap + (size_t)(m_base + row) * DIMN + k0 + gsw * 8, &As[c * 512]);
      async16(Wp + (size_t)(nloc + row) * DIMN + k0 + gsw * 8, &Bs[c * 512]);
    }
    __syncthreads();
#pragma unroll
    for (int kb = 0; kb < 2; ++kb) {
      bf16x8 af[4], bfr[4];
      const int ph = ((kb * 4 + hi) ^ (lo & 7)) * 8;
#pragma unroll
      for (int mi = 0; mi < 4; mi++)
        af[mi] = *(const bf16x8*)&As[(m0w + mi * 16 + lo) * 64 + ph];
#pragma unroll
      for (int ni = 0; ni < 4; ni++)
        bfr[ni] = *(const bf16x8*)&Bs[(n0w + ni * 16 + lo) * 64 + ph];
#pragma unroll
      for (int mi = 0; mi < 4; mi++)
#pragma unroll
        for (int ni = 0; ni < 4; ni++)
          acc[mi][ni] = __builtin_amdgcn_mfma_f32_16x16x32_bf16(af[mi], bfr[ni], acc[mi][ni], 0, 0, 0);
    }
    __syncthreads();
  }

  // ---- epilogue: wave-private 64x64 bounce + fused RoPE ----
  short* Sw = (wv < 2) ? &As[wv * 4096] : &Bs[(wv - 2) * 4096];
  const int nl0 = nloc + n0w;
  const int h  = nl0 >> 7;
  const int d0 = nl0 & 127;
  const int b  = m_base >> 11;
  const int sb = (m_base + m0w) & 2047;

#pragma unroll
  for (int mi = 0; mi < 4; mi++)
#pragma unroll
    for (int ni = 0; ni < 4; ni++)
#pragma unroll
      for (int r = 0; r < 4; r++) {
        const int ml = mi * 16 + hi * 4 + r;
        const int nl = ni * 16 + lo;
        Sw[ml * 64 + (((nl >> 3) ^ (ml & 7)) * 8) + (nl & 7)] = f2bf(acc[mi][ni][r]);
      }
  const float qs = (proj == 0) ? QSCALE : 1.0f;
  short* Out = ((proj == 0) ? Qb : Kb) + (size_t)(b * NH + h) * SEQ * HDIM;
#pragma unroll
  for (int j = 0; j < 8; ++j) {
    const int rloc = (lane >> 3) + 8 * j;
    const int sg = sb + rloc;
    const int cc = lane & 7;
    const bf16x8 v = *(const bf16x8*)&Sw[rloc * 64 + ((cc ^ (rloc & 7)) * 8)];
    const int d2b = (d0 + cc * 8) >> 1;
    const float4 c4 = *(const float4*)&fc[sg * 64 + d2b];
    const float4 s4 = *(const float4*)&fs[sg * 64 + d2b];
    int4 o;
    { const float xr = bf2f(v[0]), xi = bf2f(v[1]);
      o.x = (int)packbf((xr * c4.x - xi * s4.x) * qs, (xr * s4.x + xi * c4.x) * qs); }
    { const float xr = bf2f(v[2]), xi = bf2f(v[3]);
      o.y = (int)packbf((xr * c4.y - xi * s4.y) * qs, (xr * s4.y + xi * c4.y) * qs); }
    { const float xr = bf2f(v[4]), xi = bf2f(v[5]);
      o.z = (int)packbf((xr * c4.z - xi * s4.z) * qs, (xr * s4.z + xi * c4.z) * qs); }
    { const float xr = bf2f(v[6]), xi = bf2f(v[7]);
      o.w = (int)packbf((xr * c4.w - xi * s4.w) * qs, (xr * s4.w + xi * c4.w) * qs); }
    *(int4*)&Out[(size_t)sg * HDIM + d0 + cc * 8] = o;
  }
}

// ---- V GEMM: Vt[b,h,d,s] from X @ Wv^T, 2-phase 128^2; runs LAST so Vt
// is L2-resident when attn starts (R12-vs-R13 A/B evidence) ----
__global__ __launch_bounds__(256, 4)
void k_gemm_v(const void* __restrict__ xraw, const short* __restrict__ Xb,
              const void* __restrict__ wvraw, const short* __restrict__ Wcvt,
              short* __restrict__ Vtb, const int* __restrict__ flagp) {
  __shared__ short As[128 * 64];
  __shared__ short Bs[128 * 64];
  const int tid = threadIdx.x, lane = tid & 63, wv = tid >> 6;
  const int lo = lane & 15, hi = lane >> 4;
  const int m_base = blockIdx.y * 128;
  const int nloc = blockIdx.x * 128;          // within V's 2048 cols
  const int m0w = (wv >> 1) * 64, n0w = (wv & 1) * 64;
  const int rr = lane >> 3;
  const int gsw = (lane & 7) ^ (rr & 7);

  const int fl = *flagp;
  const short* Ap = fl ? (const short*)xraw : Xb;
  const short* Wp = fl ? (const short*)wvraw : (Wcvt + (size_t)2 * 4194304);

  f32x4 acc[4][4];
#pragma unroll
  for (int i = 0; i < 4; i++)
#pragma unroll
    for (int j = 0; j < 4; j++) acc[i][j] = (f32x4)0.0f;

  for (int k0 = 0; k0 < DIMN; k0 += 64) {
#pragma unroll
    for (int i = 0; i < 4; ++i) {
      const int c = wv * 4 + i;
      const int row = c * 8 + rr;
      async16(Ap + (size_t)(m_base + row) * DIMN + k0 + gsw * 8, &As[c * 512]);
      async16(Wp + (size_t)(nloc + row) * DIMN + k0 + gsw * 8, &Bs[c * 512]);
    }
    __syncthreads();
#pragma unroll
    for (int kb = 0; kb < 2; ++kb) {
      bf16x8 af[4], bfr[4];
      const int ph = ((kb * 4 + hi) ^ (lo & 7)) * 8;
#pragma unroll
      for (int mi = 0; mi < 4; mi++)
        af[mi] = *(const bf16x8*)&As[(m0w + mi * 16 + lo) * 64 + ph];
#pragma unroll
      for (int ni = 0; ni < 4; ni++)
        bfr[ni] = *(const bf16x8*)&Bs[(n0w + ni * 16 + lo) * 64 + ph];
#pragma unroll
      for (int mi = 0; mi < 4; mi++)
#pragma unroll
        for (int ni = 0; ni < 4; ni++)
          acc[mi][ni] = __builtin_amdgcn_mfma_f32_16x16x32_bf16(af[mi], bfr[ni], acc[mi][ni], 0, 0, 0);
    }
    __syncthreads();
  }

  // epilogue: transpose in wave-private bounce -> Vt[b,h,d,s]
  short* Sw = (wv < 2) ? &As[wv * 4096] : &Bs[(wv - 2) * 4096];
  const int nl0 = nloc + n0w;
  const int h  = nl0 >> 7;
  const int d0 = nl0 & 127;
  const int b  = m_base >> 11;
  const int sb = (m_base + m0w) & 2047;
#pragma unroll
  for (int mi = 0; mi < 4; mi++)
#pragma unroll
    for (int ni = 0; ni < 4; ni++)
#pragma unroll
      for (int r = 0; r < 4; r++) {
        const int dl = ni * 16 + lo;
        const int sl = mi * 16 + hi * 4 + r;
        Sw[dl * 64 + (((sl >> 3) ^ (dl & 7)) * 8) + (sl & 7)] = f2bf(acc[mi][ni][r]);
      }
  short* OutV = Vtb + (size_t)(b * NH + h) * HDIM * SEQ;
#pragma unroll
  for (int j = 0; j < 8; ++j) {
    const int dl = (lane >> 3) + 8 * j;
    const int cc = lane & 7;
    const int4 v = *(const int4*)&Sw[dl * 64 + ((cc ^ (dl & 7)) * 8)];
    *(int4*)&OutV[(size_t)(d0 + dl) * SEQ + sb + cc * 8] = v;
  }
}

// ---- Wo GEMM: out[M=4096, N=2048]; W selected per flag; bf16 path uses
// LDS-bounce dwordx4 epilogue, fp32 path scalar stores ----
__global__ __launch_bounds__(256, 4)
void k_gemm_wo(const short* __restrict__ A, const void* __restrict__ woraw,
               const short* __restrict__ Wcvt,
               void* __restrict__ out, const int* __restrict__ flagp) {
  __shared__ short As[128 * 64];
  __shared__ short Bs[128 * 64];
  const int tid = threadIdx.x, lane = tid & 63, wv = tid >> 6;
  const int lo = lane & 15, hi = lane >> 4;
  const int m_base = blockIdx.y * 128, n_base = blockIdx.x * 128;
  const int m0w = (wv >> 1) * 64, n0w = (wv & 1) * 64;
  const int rr = lane >> 3;
  const int gsw = (lane & 7) ^ (rr & 7);

  const int fl = *flagp;
  const short* Wp = fl ? (const short*)woraw : Wcvt;

  f32x4 acc[4][4];
#pragma unroll
  for (int i = 0; i < 4; i++)
#pragma unroll
    for (int j = 0; j < 4; j++) acc[i][j] = (f32x4)0.0f;

  for (int k0 = 0; k0 < DIMN; k0 += 64) {
#pragma unroll
    for (int i = 0; i < 4; ++i) {
      const int c = wv * 4 + i;
      const int row = c * 8 + rr;
      async16(A + (size_t)(m_base + row) * DIMN + k0 + gsw * 8, &As[c * 512]);
      async16(Wp + (size_t)(n_base + row) * DIMN + k0 + gsw * 8, &Bs[c * 512]);
    }
    __syncthreads();
#pragma unroll
    for (int kb = 0; kb < 2; ++kb) {
      bf16x8 af[4], bfr[4];
      const int ph = ((kb * 4 + hi) ^ (lo & 7)) * 8;
#pragma unroll
      for (int mi = 0; mi < 4; mi++)
        af[mi] = *(const bf16x8*)&As[(m0w + mi * 16 + lo) * 64 + ph];
#pragma unroll
      for (int ni = 0; ni < 4; ni++)
        bfr[ni] = *(const bf16x8*)&Bs[(n0w + ni * 16 + lo) * 64 + ph];
#pragma unroll
      for (int mi = 0; mi < 4; mi++)
#pragma unroll
        for (int ni = 0; ni < 4; ni++)
          acc[mi][ni] = __builtin_amdgcn_mfma_f32_16x16x32_bf16(af[mi], bfr[ni], acc[mi][ni], 0, 0, 0);
    }
    __syncthreads();
  }

  if (fl) {
    // bf16 output: wave-private LDS bounce -> dwordx4 stores
    short* Sw = (wv < 2) ? &As[wv * 4096] : &Bs[(wv - 2) * 4096];
#pragma unroll
    for (int mi = 0; mi < 4; mi++)
#pragma unroll
      for (int ni = 0; ni < 4; ni++)
#pragma unroll
        for (int r = 0; r < 4; r++) {
          const int ml = mi * 16 + hi * 4 + r;
          const int nl = ni * 16 + lo;
          Sw[ml * 64 + (((nl >> 3) ^ (ml & 7)) * 8) + (nl & 7)] = f2bf(acc[mi][ni][r]);
        }
    short* Out = (short*)out;
    const int mb = m_base + m0w, nb = n_base + n0w;
#pragma unroll
    for (int j = 0; j < 8; ++j) {
      const int rloc = (lane >> 3) + 8 * j;
      const int cc = lane & 7;
      const int4 v = *(const int4*)&Sw[rloc * 64 + ((cc ^ (rloc & 7)) * 8)];
      *(int4*)&Out[(size_t)(mb + rloc) * DIMN + nb + cc * 8] = v;
    }
  } else {
#pragma unroll
    for (int mi = 0; mi < 4; mi++)
#pragma unroll
      for (int ni = 0; ni < 4; ni++)
#pragma unroll
        for (int r = 0; r < 4; r++) {
          const int m = m_base + m0w + mi * 16 + hi * 4 + r;
          const int n = n_base + n0w + ni * 16 + lo;
          ((float*)out)[(size_t)m * DIMN + n] = acc[mi][ni][r];
        }
  }
}

// ---- Flash attention, 16x16x32 MFMA, 32 q-rows/wave (two 16-q tiles),
// double-buffered K/V (64KB LDS, R9's verified prefetch pattern) ----
//  K LDS [2][64][128], chunk c of row R at slot c^fK(R),
//    fK(R)=(R&3)|((R>>3)&1)<<2|((R>>4)&1)<<3; QK read slot=(kd*4+g)^q15.
//  V LDS [2][128][64], chunk c of row d at slot c^(d&7); PV slot=(kc*4+g)^(q15&7).
//  Permuted-row QK (Rb=((q15>>2)<<3)+(q15&3)) -> P fully in-lane for PV.
//  Iter: prefetch it+1 -> buf^1; compute on buf; vmcnt(0)+barrier; flip.
//  Barrier covers both hazards: prefetch-done before next compute, and
//  reads-done before the buffer is overwritten two iters later.
__global__ __launch_bounds__(256, 2)
void k_attn(const short* __restrict__ Q, const short* __restrict__ K,
            const short* __restrict__ Vt, short* __restrict__ O2) {
  __shared__ short Ks[2][64 * 128];
  __shared__ short Vs[2][128 * 64];
  const int tid = threadIdx.x, lane = tid & 63, w = tid >> 6;
  const int q15 = lane & 15, g = lane >> 4;
  const int id = blockIdx.x;
  const int bh = id & 31;                 // id%8 = bh%8 -> head pinned to XCD
  const int qb = id >> 5;                 // 0..15
  const int q0 = qb * 128 + w * 32;       // wave owns 32 q-rows

  // Q fragments for both 16-q tiles: lane needs Q[q0+qt*16+q15][kd*32+g*8..+8]
  bf16x8 bq[2][4];
#pragma unroll
  for (int qt = 0; qt < 2; ++qt) {
    const short* Qrow = Q + ((size_t)bh * SEQ + q0 + qt * 16 + q15) * HDIM + g * 8;
#pragma unroll
    for (int kd = 0; kd < 4; ++kd) bq[qt][kd] = *(const bf16x8*)(Qrow + kd * 32);
  }

  f32x4 oacc[2][8];
#pragma unroll
  for (int qt = 0; qt < 2; ++qt)
#pragma unroll
    for (int dt = 0; dt < 8; ++dt) oacc[qt][dt] = (f32x4)0.0f;
  float lsA[2] = {0.0f, 0.0f};
  float lsB[2] = {0.0f, 0.0f};

  const short* Kbase = K  + (size_t)bh * SEQ * HDIM;
  const short* Vbase = Vt + (size_t)bh * HDIM * SEQ;

  // staging lane constants (4 waves cover the 64x128 K + 128x64 V tile)
  const int krl = lane >> 4;                              // row within quad
  const int kc0 = (lane & 15) ^ krl ^ ((w & 1) << 3);     // ^((i>>1)<<2) per call
  const int vrow = lane >> 3;                             // 0..7
  const int vc   = (lane & 7) ^ vrow;
  // QK read: phys row base p16(q15)
  const int Rb = ((q15 >> 2) << 3) + (q15 & 3);

  // prologue: stage tile 0 -> buf 0
#pragma unroll
  for (int i = 0; i < 4; ++i) {
    const int R = w * 16 + i * 4 + krl;
    const int c = kc0 ^ ((i >> 1) << 2);
    async16(Kbase + (size_t)R * HDIM + c * 8, &Ks[0][(w * 16 + i * 4) * 128]);
    const int rV = (w * 4 + i) * 8 + vrow;
    async16(Vbase + (size_t)rV * SEQ + vc * 8, &Vs[0][(w * 4 + i) * 512]);
  }
  asm volatile("s_waitcnt vmcnt(0)" ::: "memory");
  asm volatile("s_barrier" ::: "memory");

  int cur = 0;
#pragma unroll 1
  for (int it = 0; it < SEQ / 64; ++it) {
    // prefetch next tile into buf cur^1 (that buffer's readers finished at
    // the barrier ending iter it-1)
    if (it + 1 < SEQ / 64) {
      const int kv1 = (it + 1) * 64;
#pragma unroll
      for (int i = 0; i < 4; ++i) {
        const int R = w * 16 + i * 4 + krl;
        const int c = kc0 ^ ((i >> 1) << 2);
        async16(Kbase + (size_t)(kv1 + R) * HDIM + c * 8,
                &Ks[cur ^ 1][(w * 16 + i * 4) * 128]);
        const int rV = (w * 4 + i) * 8 + vrow;
        async16(Vbase + (size_t)rV * SEQ + kv1 + vc * 8,
                &Vs[cur ^ 1][(w * 4 + i) * 512]);
      }
    }

    // QK^T: sacc[qt][kc][h]; each ak read feeds both q-tiles
    f32x4 sacc[2][2][2];
#pragma unroll
    for (int qt = 0; qt < 2; ++qt)
#pragma unroll
      for (int kc = 0; kc < 2; ++kc)
#pragma unroll
        for (int h = 0; h < 2; ++h) sacc[qt][kc][h] = (f32x4)0.0f;
    __builtin_amdgcn_s_setprio(1);
#pragma unroll
    for (int kd = 0; kd < 4; ++kd) {
      const int sl = ((kd * 4 + g) ^ q15) * 8;
#pragma unroll
      for (int kc = 0; kc < 2; ++kc)
#pragma unroll
        for (int h = 0; h < 2; ++h) {
          const bf16x8 ak = *(const bf16x8*)&Ks[cur][(Rb + h * 4 + kc * 32) * 128 + sl];
          sacc[0][kc][h] = __builtin_amdgcn_mfma_f32_16x16x32_bf16(ak, bq[0][kd], sacc[0][kc][h], 0, 0, 0);
          sacc[1][kc][h] = __builtin_amdgcn_mfma_f32_16x16x32_bf16(ak, bq[1][kd], sacc[1][kc][h], 0, 0, 0);
        }
    }
    __builtin_amdgcn_s_setprio(0);

    // exp + partial sums + bf16 pack (all in-lane; e = h*4+r ordering)
    bf16x8 bp[2][2];
#pragma unroll
    for (int qt = 0; qt < 2; ++qt)
#pragma unroll
      for (int kc = 0; kc < 2; ++kc) {
        const float a0 = __expf(sacc[qt][kc][0][0]), a1 = __expf(sacc[qt][kc][0][1]);
        const float a2 = __expf(sacc[qt][kc][0][2]), a3 = __expf(sacc[qt][kc][0][3]);
        const float b0 = __expf(sacc[qt][kc][1][0]), b1 = __expf(sacc[qt][kc][1][1]);
        const float b2 = __expf(sacc[qt][kc][1][2]), b3 = __expf(sacc[qt][kc][1][3]);
        lsA[qt] += (a0 + a1) + (a2 + a3);
        lsB[qt] += (b0 + b1) + (b2 + b3);
        unsigned w0, w1, w2, w3;
        asm("v_cvt_pk_bf16_f32 %0, %1, %2" : "=v"(w0) : "v"(a0), "v"(a1));
        asm("v_cvt_pk_bf16_f32 %0, %1, %2" : "=v"(w1) : "v"(a2), "v"(a3));
        asm("v_cvt_pk_bf16_f32 %0, %1, %2" : "=v"(w2) : "v"(b0), "v"(b1));
        asm("v_cvt_pk_bf16_f32 %0, %1, %2" : "=v"(w3) : "v"(b2), "v"(b3));
        union { int4 i4; bf16x8 b; } pu;
        pu.i4.x = (int)w0; pu.i4.y = (int)w1;   // kv offsets e=0..3 (h=0)
        pu.i4.z = (int)w2; pu.i4.w = (int)w3;   // kv offsets e=4..7 (h=1)
        bp[qt][kc] = pu.b;
      }

    // PV: each av read feeds both q-tiles
    __builtin_amdgcn_s_setprio(1);
#pragma unroll
    for (int kc = 0; kc < 2; ++kc) {
      const int slv = ((kc * 4 + g) ^ (q15 & 7)) * 8;
#pragma unroll
      for (int dt = 0; dt < 8; ++dt) {
        const bf16x8 av = *(const bf16x8*)&Vs[cur][(dt * 16 + q15) * 64 + slv];
        oacc[0][dt] = __builtin_amdgcn_mfma_f32_16x16x32_bf16(av, bp[0][kc], oacc[0][dt], 0, 0, 0);
        oacc[1][dt] = __builtin_amdgcn_mfma_f32_16x16x32_bf16(av, bp[1][kc], oacc[1][dt], 0, 0, 0);
      }
    }
    __builtin_amdgcn_s_setprio(0);

    asm volatile("s_waitcnt vmcnt(0)" ::: "memory");  // prefetch covered by compute
    asm volatile("s_barrier" ::: "memory");
    cur ^= 1;
  }

  // column sums l(q) per q-tile: reduce across the 4 g-lanes of column q15
  const int b = bh >> 4, h = bh & 15;
#pragma unroll
  for (int qt = 0; qt < 2; ++qt) {
    float ls = lsA[qt] + lsB[qt];
    ls += __shfl_xor(ls, 16);
    ls += __shfl_xor(ls, 32);
    const float inv = 1.0f / ls;
    // lane holds O[d = dt*16 + g*4 + r][q15] -> O2[b, s=q0+qt*16+q15, h*128+d]
    short* ob = O2 + ((size_t)(b * SEQ + q0 + qt * 16 + q15) * DIMN + h * HDIM + g * 4);
#pragma unroll
    for (int dt = 0; dt < 8; ++dt) {
      const unsigned w0 = packbf(oacc[qt][dt][0] * inv, oacc[qt][dt][1] * inv);
      const unsigned w1 = packbf(oacc[qt][dt][2] * inv, oacc[qt][dt][3] * inv);
      *(unsigned long long*)&ob[dt * 16] = (unsigned long long)w0 | ((unsigned long long)w1 << 32);
    }
  }
}

// ---- workspace layout (bytes) ----
#define OFF_FLAG 0
#define OFF_FC   1024
#define OFF_FS   (OFF_FC + 524288)
#define OFF_XB   (OFF_FS + 524288)
#define OFF_WQKV (OFF_XB + 16777216)
#define OFF_WO   (OFF_WQKV + 25165824)
#define OFF_Q    (OFF_WO + 8388608)
#define OFF_K    (OFF_Q  + 16777216)
#define OFF_VT   (OFF_K  + 16777216)
#define OFF_O2   (OFF_VT + 16777216)

extern "C" void kernel_launch(void* const* d_in, const int* in_sizes, int n_in,
                              void* d_out, int out_size, void* d_ws, size_t ws_size,
                              hipStream_t stream) {
  (void)in_sizes; (void)n_in; (void)out_size; (void)ws_size;
  char* ws = (char*)d_ws;
  int*   flag = (int*)(ws + OFF_FLAG);
  float* fc   = (float*)(ws + OFF_FC);
  float* fs   = (float*)(ws + OFF_FS);
  short* Xb   = (short*)(ws + OFF_XB);
  short* Wqkv = (short*)(ws + OFF_WQKV);
  short* Wo   = (short*)(ws + OFF_WO);
  short* Qb   = (short*)(ws + OFF_Q);
  short* Kb   = (short*)(ws + OFF_K);
  short* Vtb  = (short*)(ws + OFF_VT);
  short* O2   = (short*)(ws + OFF_O2);

  k_cvt_fused<<<25600, 256, 0, stream>>>(d_in[0], d_in[4], d_in[5], d_in[6], d_in[7],
                                         d_in[1], d_in[2],
                                         (unsigned long long*)Xb,
                                         (unsigned long long*)Wqkv,
                                         (unsigned long long*)Wo, fc, fs, flag);

  k_gemm_qk2<<<dim3(32, 32), 256, 0, stream>>>(d_in[0], Xb,
                                               d_in[4], d_in[5], Wqkv,
                                               Qb, Kb, fc, fs, flag);

  k_gemm_v<<<dim3(16, 32), 256, 0, stream>>>(d_in[0], Xb, d_in[6], Wqkv, Vtb, flag);

  k_attn<<<512, 256, 0, stream>>>(Qb, Kb, Vtb, O2);

  k_gemm_wo<<<dim3(16, 32), 256, 0, stream>>>(O2, d_in[7], Wo, d_out, flag);
}

// Round 10
// 381.212 us; speedup vs baseline: 1.0211x; 1.0211x over previous
//
#include <hip/hip_runtime.h>

// MHA forward: x@Wq^T/Wk^T/Wv^T -> RoPE(q,k) -> softmax(qk^T/sqrt(hd))v -> @Wo^T
// B=2 H=16 S=2048 D=2048 HD=128. bf16 MFMA, fp32 accum.
// R15: lock-in round. R12's exact config (best measured total, 363us) with
// its one measured-inferior component swapped: qk 8-phase (89.5us) -> qk2
// 2-phase 128^2 (<=78us, measured R14). Attn reverts to R12's byte-identical
// single-buffered two-tile (dbuf was 2x-replicated neutral at 2 waves/SIMD;
// 32KB LDS). v stays before attn (Vt L2-warm), wo last. Env note: totals
// carry ~+/-20us of harness-gap noise (R13/R14 drew ~+35us vs R8/R12 runs).

#define DIMN 2048
#define SEQ  2048
#define NH   16
#define HDIM 128
#define NB   2
#define TOK  (NB*SEQ)          // 4096
#define QSCALE 0.08838834764831845f

typedef __attribute__((ext_vector_type(8)))  short bf16x8;
typedef __attribute__((ext_vector_type(4)))  float f32x4;
typedef __attribute__((ext_vector_type(16))) float f32x16;

__device__ __forceinline__ short f2bf(float f) {
  union { float f; unsigned u; } v; v.f = f;
  unsigned r = v.u + 0x7FFFu + ((v.u >> 16) & 1u);   // RNE
  return (short)(r >> 16);
}
__device__ __forceinline__ float bf2f(short b) {
  union { unsigned u; float f; } v; v.u = ((unsigned)(unsigned short)b) << 16;
  return v.f;
}
__device__ __forceinline__ unsigned packbf(float a, float b) {  // RNE pack
  union { float f; unsigned u; } x, y; x.f = a; y.f = b;
  unsigned ua = x.u + 0x7FFFu + ((x.u >> 16) & 1u);
  unsigned ub = y.u + 0x7FFFu + ((y.u >> 16) & 1u);
  return (ua >> 16) | (ub & 0xFFFF0000u);
}
__device__ __forceinline__ void async16(const void* g, void* l) {
  __builtin_amdgcn_global_load_lds(
      (const __attribute__((address_space(1))) unsigned*)g,
      (__attribute__((address_space(3))) unsigned*)l, 16, 0, 0);
}
// per-wave dtype detect from first 1KB of x: 1 = bf16 inputs
__device__ __forceinline__ int detect_bf16(const unsigned* x32) {
  const int lane = threadIdx.x & 63;
  int cnt = 0;
#pragma unroll
  for (int i = 0; i < 4; ++i) {
    unsigned w = x32[lane * 4 + i];
    unsigned e = (w >> 7) & 0xFFu;
    cnt += (e >= 90u && e <= 160u) ? 1 : 0;
  }
#pragma unroll
  for (int o = 1; o < 64; o <<= 1) cnt += __shfl_xor(cnt, o);
  return cnt > 180;
}

// ---- convert x + 4 weights (+freqs); copy blocks are no-ops in bf16 mode ----
__global__ void k_cvt_fused(const void* __restrict__ x,  const void* __restrict__ wq,
                            const void* __restrict__ wk, const void* __restrict__ wv,
                            const void* __restrict__ wo,
                            const void* __restrict__ cfr, const void* __restrict__ sfr,
                            unsigned long long* __restrict__ Xb,
                            unsigned long long* __restrict__ Wqkv,
                            unsigned long long* __restrict__ Wo,
                            float* __restrict__ fc, float* __restrict__ fs,
                            int* __restrict__ flagout) {
  const int fl = detect_bf16((const unsigned*)x);
  const int blk = blockIdx.x;
  if (blk == 0 && threadIdx.x == 0) *flagout = fl;
  if (blk >= 24576) {                       // freqs: fp32 outputs (always)
    const int fb = blk - 24576;
    const void* src = (fb < 512) ? cfr : sfr;
    float* dst = (fb < 512) ? fc : fs;
    const int i = (fb & 511) * 256 + threadIdx.x;
    dst[i] = fl ? bf2f(((const short*)src)[i]) : ((const float*)src)[i];
    return;
  }
  if (fl) return;                           // bf16 inputs: GEMMs read d_in directly
  const void* src; unsigned long long* dst; int base;
  if      (blk <  8192) { src = x;  dst = Xb;             base = blk;          }
  else if (blk < 12288) { src = wq; dst = Wqkv;           base = blk - 8192;   }
  else if (blk < 16384) { src = wk; dst = Wqkv + 1048576; base = blk - 12288;  }
  else if (blk < 20480) { src = wv; dst = Wqkv + 2097152; base = blk - 16384;  }
  else                  { src = wo; dst = Wo;             base = blk - 20480;  }
  const int i = base * 256 + threadIdx.x;
  float4 v = ((const float4*)src)[i];
  dst[i] = (unsigned long long)(unsigned)packbf(v.x, v.y)
         | ((unsigned long long)(unsigned)packbf(v.z, v.w) << 32);
}

// ---- Q+K GEMM: C[M=4096, N=4096] = X @ [Wq;Wk]^T, 2-phase 128^2 ----
// The 904-TF-measured structure restricted to the Q/K region.
// Grid 32x32 = 1024 blocks = exactly one round at 4 blocks/CU.
// Epilogue: wave-private LDS bounce + fused RoPE (Q scaled by QSCALE).
__global__ __launch_bounds__(256, 4)
void k_gemm_qk2(const void* __restrict__ xraw, const short* __restrict__ Xb,
                const void* __restrict__ wqraw, const void* __restrict__ wkraw,
                const short* __restrict__ Wcvt,
                short* __restrict__ Qb, short* __restrict__ Kb,
                const float* __restrict__ fc, const float* __restrict__ fs,
                const int* __restrict__ flagp) {
  __shared__ short As[128 * 64];
  __shared__ short Bs[128 * 64];
  const int tid = threadIdx.x, lane = tid & 63, wv = tid >> 6;
  const int lo = lane & 15, hi = lane >> 4;
  const int m_base = blockIdx.y * 128, n_base = blockIdx.x * 128;
  const int m0w = (wv >> 1) * 64, n0w = (wv & 1) * 64;
  const int rr = lane >> 3;
  const int gsw = (lane & 7) ^ (rr & 7);
  const int proj = n_base >> 11;              // 0=Q 1=K
  const int nloc = n_base & 2047;

  const int fl = *flagp;
  const short* Ap = fl ? (const short*)xraw : Xb;
  const short* Wp = fl ? (const short*)((proj == 0) ? wqraw : wkraw)
                       : (Wcvt + (size_t)proj * 4194304);

  f32x4 acc[4][4];
#pragma unroll
  for (int i = 0; i < 4; i++)
#pragma unroll
    for (int j = 0; j < 4; j++) acc[i][j] = (f32x4)0.0f;

  for (int k0 = 0; k0 < DIMN; k0 += 64) {
#pragma unroll
    for (int i = 0; i < 4; ++i) {
      const int c = wv * 4 + i;
      const int row = c * 8 + rr;
      async16(Ap + (size_t)(m_base + row) * DIMN + k0 + gsw * 8, &As[c * 512]);
      async16(Wp + (size_t)(nloc + row) * DIMN + k0 + gsw * 8, &Bs[c * 512]);
    }
    __syncthreads();
#pragma unroll
    for (int kb = 0; kb < 2; ++kb) {
      bf16x8 af[4], bfr[4];
      const int ph = ((kb * 4 + hi) ^ (lo & 7)) * 8;
#pragma unroll
      for (int mi = 0; mi < 4; mi++)
        af[mi] = *(const bf16x8*)&As[(m0w + mi * 16 + lo) * 64 + ph];
#pragma unroll
      for (int ni = 0; ni < 4; ni++)
        bfr[ni] = *(const bf16x8*)&Bs[(n0w + ni * 16 + lo) * 64 + ph];
#pragma unroll
      for (int mi = 0; mi < 4; mi++)
#pragma unroll
        for (int ni = 0; ni < 4; ni++)
          acc[mi][ni] = __builtin_amdgcn_mfma_f32_16x16x32_bf16(af[mi], bfr[ni], acc[mi][ni], 0, 0, 0);
    }
    __syncthreads();
  }

  // ---- epilogue: wave-private 64x64 bounce + fused RoPE ----
  short* Sw = (wv < 2) ? &As[wv * 4096] : &Bs[(wv - 2) * 4096];
  const int nl0 = nloc + n0w;
  const int h  = nl0 >> 7;
  const int d0 = nl0 & 127;
  const int b  = m_base >> 11;
  const int sb = (m_base + m0w) & 2047;

#pragma unroll
  for (int mi = 0; mi < 4; mi++)
#pragma unroll
    for (int ni = 0; ni < 4; ni++)
#pragma unroll
      for (int r = 0; r < 4; r++) {
        const int ml = mi * 16 + hi * 4 + r;
        const int nl = ni * 16 + lo;
        Sw[ml * 64 + (((nl >> 3) ^ (ml & 7)) * 8) + (nl & 7)] = f2bf(acc[mi][ni][r]);
      }
  const float qs = (proj == 0) ? QSCALE : 1.0f;
  short* Out = ((proj == 0) ? Qb : Kb) + (size_t)(b * NH + h) * SEQ * HDIM;
#pragma unroll
  for (int j = 0; j < 8; ++j) {
    const int rloc = (lane >> 3) + 8 * j;
    const int sg = sb + rloc;
    const int cc = lane & 7;
    const bf16x8 v = *(const bf16x8*)&Sw[rloc * 64 + ((cc ^ (rloc & 7)) * 8)];
    const int d2b = (d0 + cc * 8) >> 1;
    const float4 c4 = *(const float4*)&fc[sg * 64 + d2b];
    const float4 s4 = *(const float4*)&fs[sg * 64 + d2b];
    int4 o;
    { const float xr = bf2f(v[0]), xi = bf2f(v[1]);
      o.x = (int)packbf((xr * c4.x - xi * s4.x) * qs, (xr * s4.x + xi * c4.x) * qs); }
    { const float xr = bf2f(v[2]), xi = bf2f(v[3]);
      o.y = (int)packbf((xr * c4.y - xi * s4.y) * qs, (xr * s4.y + xi * c4.y) * qs); }
    { const float xr = bf2f(v[4]), xi = bf2f(v[5]);
      o.z = (int)packbf((xr * c4.z - xi * s4.z) * qs, (xr * s4.z + xi * c4.z) * qs); }
    { const float xr = bf2f(v[6]), xi = bf2f(v[7]);
      o.w = (int)packbf((xr * c4.w - xi * s4.w) * qs, (xr * s4.w + xi * c4.w) * qs); }
    *(int4*)&Out[(size_t)sg * HDIM + d0 + cc * 8] = o;
  }
}

// ---- V GEMM: Vt[b,h,d,s] from X @ Wv^T, 2-phase 128^2; runs right before
// attn so Vt is L2-resident when attn starts (R12-vs-R13 A/B evidence) ----
__global__ __launch_bounds__(256, 4)
void k_gemm_v(const void* __restrict__ xraw, const short* __restrict__ Xb,
              const void* __restrict__ wvraw, const short* __restrict__ Wcvt,
              short* __restrict__ Vtb, const int* __restrict__ flagp) {
  __shared__ short As[128 * 64];
  __shared__ short Bs[128 * 64];
  const int tid = threadIdx.x, lane = tid & 63, wv = tid >> 6;
  const int lo = lane & 15, hi = lane >> 4;
  const int m_base = blockIdx.y * 128;
  const int nloc = blockIdx.x * 128;          // within V's 2048 cols
  const int m0w = (wv >> 1) * 64, n0w = (wv & 1) * 64;
  const int rr = lane >> 3;
  const int gsw = (lane & 7) ^ (rr & 7);

  const int fl = *flagp;
  const short* Ap = fl ? (const short*)xraw : Xb;
  const short* Wp = fl ? (const short*)wvraw : (Wcvt + (size_t)2 * 4194304);

  f32x4 acc[4][4];
#pragma unroll
  for (int i = 0; i < 4; i++)
#pragma unroll
    for (int j = 0; j < 4; j++) acc[i][j] = (f32x4)0.0f;

  for (int k0 = 0; k0 < DIMN; k0 += 64) {
#pragma unroll
    for (int i = 0; i < 4; ++i) {
      const int c = wv * 4 + i;
      const int row = c * 8 + rr;
      async16(Ap + (size_t)(m_base + row) * DIMN + k0 + gsw * 8, &As[c * 512]);
      async16(Wp + (size_t)(nloc + row) * DIMN + k0 + gsw * 8, &Bs[c * 512]);
    }
    __syncthreads();
#pragma unroll
    for (int kb = 0; kb < 2; ++kb) {
      bf16x8 af[4], bfr[4];
      const int ph = ((kb * 4 + hi) ^ (lo & 7)) * 8;
#pragma unroll
      for (int mi = 0; mi < 4; mi++)
        af[mi] = *(const bf16x8*)&As[(m0w + mi * 16 + lo) * 64 + ph];
#pragma unroll
      for (int ni = 0; ni < 4; ni++)
        bfr[ni] = *(const bf16x8*)&Bs[(n0w + ni * 16 + lo) * 64 + ph];
#pragma unroll
      for (int mi = 0; mi < 4; mi++)
#pragma unroll
        for (int ni = 0; ni < 4; ni++)
          acc[mi][ni] = __builtin_amdgcn_mfma_f32_16x16x32_bf16(af[mi], bfr[ni], acc[mi][ni], 0, 0, 0);
    }
    __syncthreads();
  }

  // epilogue: transpose in wave-private bounce -> Vt[b,h,d,s]
  short* Sw = (wv < 2) ? &As[wv * 4096] : &Bs[(wv - 2) * 4096];
  const int nl0 = nloc + n0w;
  const int h  = nl0 >> 7;
  const int d0 = nl0 & 127;
  const int b  = m_base >> 11;
  const int sb = (m_base + m0w) & 2047;
#pragma unroll
  for (int mi = 0; mi < 4; mi++)
#pragma unroll
    for (int ni = 0; ni < 4; ni++)
#pragma unroll
      for (int r = 0; r < 4; r++) {
        const int dl = ni * 16 + lo;
        const int sl = mi * 16 + hi * 4 + r;
        Sw[dl * 64 + (((sl >> 3) ^ (dl & 7)) * 8) + (sl & 7)] = f2bf(acc[mi][ni][r]);
      }
  short* OutV = Vtb + (size_t)(b * NH + h) * HDIM * SEQ;
#pragma unroll
  for (int j = 0; j < 8; ++j) {
    const int dl = (lane >> 3) + 8 * j;
    const int cc = lane & 7;
    const int4 v = *(const int4*)&Sw[dl * 64 + ((cc ^ (dl & 7)) * 8)];
    *(int4*)&OutV[(size_t)(d0 + dl) * SEQ + sb + cc * 8] = v;
  }
}

// ---- Wo GEMM: out[M=4096, N=2048]; W selected per flag; bf16 path uses
// LDS-bounce dwordx4 epilogue, fp32 path scalar stores ----
__global__ __launch_bounds__(256, 4)
void k_gemm_wo(const short* __restrict__ A, const void* __restrict__ woraw,
               const short* __restrict__ Wcvt,
               void* __restrict__ out, const int* __restrict__ flagp) {
  __shared__ short As[128 * 64];
  __shared__ short Bs[128 * 64];
  const int tid = threadIdx.x, lane = tid & 63, wv = tid >> 6;
  const int lo = lane & 15, hi = lane >> 4;
  const int m_base = blockIdx.y * 128, n_base = blockIdx.x * 128;
  const int m0w = (wv >> 1) * 64, n0w = (wv & 1) * 64;
  const int rr = lane >> 3;
  const int gsw = (lane & 7) ^ (rr & 7);

  const int fl = *flagp;
  const short* Wp = fl ? (const short*)woraw : Wcvt;

  f32x4 acc[4][4];
#pragma unroll
  for (int i = 0; i < 4; i++)
#pragma unroll
    for (int j = 0; j < 4; j++) acc[i][j] = (f32x4)0.0f;

  for (int k0 = 0; k0 < DIMN; k0 += 64) {
#pragma unroll
    for (int i = 0; i < 4; ++i) {
      const int c = wv * 4 + i;
      const int row = c * 8 + rr;
      async16(A + (size_t)(m_base + row) * DIMN + k0 + gsw * 8, &As[c * 512]);
      async16(Wp + (size_t)(n_base + row) * DIMN + k0 + gsw * 8, &Bs[c * 512]);
    }
    __syncthreads();
#pragma unroll
    for (int kb = 0; kb < 2; ++kb) {
      bf16x8 af[4], bfr[4];
      const int ph = ((kb * 4 + hi) ^ (lo & 7)) * 8;
#pragma unroll
      for (int mi = 0; mi < 4; mi++)
        af[mi] = *(const bf16x8*)&As[(m0w + mi * 16 + lo) * 64 + ph];
#pragma unroll
      for (int ni = 0; ni < 4; ni++)
        bfr[ni] = *(const bf16x8*)&Bs[(n0w + ni * 16 + lo) * 64 + ph];
#pragma unroll
      for (int mi = 0; mi < 4; mi++)
#pragma unroll
        for (int ni = 0; ni < 4; ni++)
          acc[mi][ni] = __builtin_amdgcn_mfma_f32_16x16x32_bf16(af[mi], bfr[ni], acc[mi][ni], 0, 0, 0);
    }
    __syncthreads();
  }

  if (fl) {
    // bf16 output: wave-private LDS bounce -> dwordx4 stores
    short* Sw = (wv < 2) ? &As[wv * 4096] : &Bs[(wv - 2) * 4096];
#pragma unroll
    for (int mi = 0; mi < 4; mi++)
#pragma unroll
      for (int ni = 0; ni < 4; ni++)
#pragma unroll
        for (int r = 0; r < 4; r++) {
          const int ml = mi * 16 + hi * 4 + r;
          const int nl = ni * 16 + lo;
          Sw[ml * 64 + (((nl >> 3) ^ (ml & 7)) * 8) + (nl & 7)] = f2bf(acc[mi][ni][r]);
        }
    short* Out = (short*)out;
    const int mb = m_base + m0w, nb = n_base + n0w;
#pragma unroll
    for (int j = 0; j < 8; ++j) {
      const int rloc = (lane >> 3) + 8 * j;
      const int cc = lane & 7;
      const int4 v = *(const int4*)&Sw[rloc * 64 + ((cc ^ (rloc & 7)) * 8)];
      *(int4*)&Out[(size_t)(mb + rloc) * DIMN + nb + cc * 8] = v;
    }
  } else {
#pragma unroll
    for (int mi = 0; mi < 4; mi++)
#pragma unroll
      for (int ni = 0; ni < 4; ni++)
#pragma unroll
        for (int r = 0; r < 4; r++) {
          const int m = m_base + m0w + mi * 16 + hi * 4 + r;
          const int n = n_base + n0w + ni * 16 + lo;
          ((float*)out)[(size_t)m * DIMN + n] = acc[mi][ni][r];
        }
  }
}

// ---- Flash attention, 16x16x32 MFMA, 32 q-rows/wave (two 16-q tiles) ----
// Byte-identical to R12's verified kernel (ran in the 363us total).
// Every K/V A-operand ds_read feeds TWO MFMAs (qt=0,1): LDS bytes/FLOP
// halved vs one-tile version. Layouts:
//  K LDS [64][128], chunk c of row R at slot c^fK(R),
//    fK(R)=(R&3)|((R>>3)&1)<<2|((R>>4)&1)<<3; QK read slot=(kd*4+g)^q15.
//  V LDS [128][64], chunk c of row d at slot c^(d&7); PV slot=(kc*4+g)^(q15&7).
//  Permuted-row QK (Rb=((q15>>2)<<3)+(q15&3)) -> P fully in-lane for PV.
__global__ __launch_bounds__(256, 2)
void k_attn(const short* __restrict__ Q, const short* __restrict__ K,
            const short* __restrict__ Vt, short* __restrict__ O2) {
  __shared__ short Ks[64 * 128];
  __shared__ short Vs[128 * 64];
  const int tid = threadIdx.x, lane = tid & 63, w = tid >> 6;
  const int q15 = lane & 15, g = lane >> 4;
  const int id = blockIdx.x;
  const int bh = id & 31;                 // id%8 = bh%8 -> head pinned to XCD
  const int qb = id >> 5;                 // 0..15
  const int q0 = qb * 128 + w * 32;       // wave owns 32 q-rows

  // Q fragments for both 16-q tiles: lane needs Q[q0+qt*16+q15][kd*32+g*8..+8]
  bf16x8 bq[2][4];
#pragma unroll
  for (int qt = 0; qt < 2; ++qt) {
    const short* Qrow = Q + ((size_t)bh * SEQ + q0 + qt * 16 + q15) * HDIM + g * 8;
#pragma unroll
    for (int kd = 0; kd < 4; ++kd) bq[qt][kd] = *(const bf16x8*)(Qrow + kd * 32);
  }

  f32x4 oacc[2][8];
#pragma unroll
  for (int qt = 0; qt < 2; ++qt)
#pragma unroll
    for (int dt = 0; dt < 8; ++dt) oacc[qt][dt] = (f32x4)0.0f;
  float lsA[2] = {0.0f, 0.0f};
  float lsB[2] = {0.0f, 0.0f};

  const short* Kbase = K  + (size_t)bh * SEQ * HDIM;
  const short* Vbase = Vt + (size_t)bh * HDIM * SEQ;

  // staging lane constants (4 waves cover the 64x128 K + 128x64 V tile)
  const int krl = lane >> 4;                              // row within quad
  const int kc0 = (lane & 15) ^ krl ^ ((w & 1) << 3);     // ^((i>>1)<<2) per call
  const int vrow = lane >> 3;                             // 0..7
  const int vc   = (lane & 7) ^ vrow;
  // QK read: phys row base p16(q15)
  const int Rb = ((q15 >> 2) << 3) + (q15 & 3);

#pragma unroll 1
  for (int it = 0; it < SEQ / 64; ++it) {
    const int kv0 = it * 64;
#pragma unroll
    for (int i = 0; i < 4; ++i) {
      const int R = w * 16 + i * 4 + krl;
      const int c = kc0 ^ ((i >> 1) << 2);
      async16(Kbase + (size_t)(kv0 + R) * HDIM + c * 8, &Ks[(w * 16 + i * 4) * 128]);
      const int rV = (w * 4 + i) * 8 + vrow;
      async16(Vbase + (size_t)rV * SEQ + kv0 + vc * 8, &Vs[(w * 4 + i) * 512]);
    }
    asm volatile("s_waitcnt vmcnt(0)" ::: "memory");
    asm volatile("s_barrier" ::: "memory");

    // QK^T: sacc[qt][kc][h]; each ak read feeds both q-tiles
    f32x4 sacc[2][2][2];
#pragma unroll
    for (int qt = 0; qt < 2; ++qt)
#pragma unroll
      for (int kc = 0; kc < 2; ++kc)
#pragma unroll
        for (int h = 0; h < 2; ++h) sacc[qt][kc][h] = (f32x4)0.0f;
    __builtin_amdgcn_s_setprio(1);
#pragma unroll
    for (int kd = 0; kd < 4; ++kd) {
      const int sl = ((kd * 4 + g) ^ q15) * 8;
#pragma unroll
      for (int kc = 0; kc < 2; ++kc)
#pragma unroll
        for (int h = 0; h < 2; ++h) {
          const bf16x8 ak = *(const bf16x8*)&Ks[(Rb + h * 4 + kc * 32) * 128 + sl];
          sacc[0][kc][h] = __builtin_amdgcn_mfma_f32_16x16x32_bf16(ak, bq[0][kd], sacc[0][kc][h], 0, 0, 0);
          sacc[1][kc][h] = __builtin_amdgcn_mfma_f32_16x16x32_bf16(ak, bq[1][kd], sacc[1][kc][h], 0, 0, 0);
        }
    }
    __builtin_amdgcn_s_setprio(0);

    // exp + partial sums + bf16 pack (all in-lane; e = h*4+r ordering)
    bf16x8 bp[2][2];
#pragma unroll
    for (int qt = 0; qt < 2; ++qt)
#pragma unroll
      for (int kc = 0; kc < 2; ++kc) {
        const float a0 = __expf(sacc[qt][kc][0][0]), a1 = __expf(sacc[qt][kc][0][1]);
        const float a2 = __expf(sacc[qt][kc][0][2]), a3 = __expf(sacc[qt][kc][0][3]);
        const float b0 = __expf(sacc[qt][kc][1][0]), b1 = __expf(sacc[qt][kc][1][1]);
        const float b2 = __expf(sacc[qt][kc][1][2]), b3 = __expf(sacc[qt][kc][1][3]);
        lsA[qt] += (a0 + a1) + (a2 + a3);
        lsB[qt] += (b0 + b1) + (b2 + b3);
        unsigned w0, w1, w2, w3;
        asm("v_cvt_pk_bf16_f32 %0, %1, %2" : "=v"(w0) : "v"(a0), "v"(a1));
        asm("v_cvt_pk_bf16_f32 %0, %1, %2" : "=v"(w1) : "v"(a2), "v"(a3));
        asm("v_cvt_pk_bf16_f32 %0, %1, %2" : "=v"(w2) : "v"(b0), "v"(b1));
        asm("v_cvt_pk_bf16_f32 %0, %1, %2" : "=v"(w3) : "v"(b2), "v"(b3));
        union { int4 i4; bf16x8 b; } pu;
        pu.i4.x = (int)w0; pu.i4.y = (int)w1;   // kv offsets e=0..3 (h=0)
        pu.i4.z = (int)w2; pu.i4.w = (int)w3;   // kv offsets e=4..7 (h=1)
        bp[qt][kc] = pu.b;
      }

    // PV: each av read feeds both q-tiles
    __builtin_amdgcn_s_setprio(1);
#pragma unroll
    for (int kc = 0; kc < 2; ++kc) {
      const int slv = ((kc * 4 + g) ^ (q15 & 7)) * 8;
#pragma unroll
      for (int dt = 0; dt < 8; ++dt) {
        const bf16x8 av = *(const bf16x8*)&Vs[(dt * 16 + q15) * 64 + slv];
        oacc[0][dt] = __builtin_amdgcn_mfma_f32_16x16x32_bf16(av, bp[0][kc], oacc[0][dt], 0, 0, 0);
        oacc[1][dt] = __builtin_amdgcn_mfma_f32_16x16x32_bf16(av, bp[1][kc], oacc[1][dt], 0, 0, 0);
      }
    }
    __builtin_amdgcn_s_setprio(0);
    asm volatile("s_barrier" ::: "memory");   // reads done before next stage
  }

  // column sums l(q) per q-tile: reduce across the 4 g-lanes of column q15
  const int b = bh >> 4, h = bh & 15;
#pragma unroll
  for (int qt = 0; qt < 2; ++qt) {
    float ls = lsA[qt] + lsB[qt];
    ls += __shfl_xor(ls, 16);
    ls += __shfl_xor(ls, 32);
    const float inv = 1.0f / ls;
    // lane holds O[d = dt*16 + g*4 + r][q15] -> O2[b, s=q0+qt*16+q15, h*128+d]
    short* ob = O2 + ((size_t)(b * SEQ + q0 + qt * 16 + q15) * DIMN + h * HDIM + g * 4);
#pragma unroll
    for (int dt = 0; dt < 8; ++dt) {
      const unsigned w0 = packbf(oacc[qt][dt][0] * inv, oacc[qt][dt][1] * inv);
      const unsigned w1 = packbf(oacc[qt][dt][2] * inv, oacc[qt][dt][3] * inv);
      *(unsigned long long*)&ob[dt * 16] = (unsigned long long)w0 | ((unsigned long long)w1 << 32);
    }
  }
}

// ---- workspace layout (bytes) ----
#define OFF_FLAG 0
#define OFF_FC   1024
#define OFF_FS   (OFF_FC + 524288)
#define OFF_XB   (OFF_FS + 524288)
#define OFF_WQKV (OFF_XB + 16777216)
#define OFF_WO   (OFF_WQKV + 25165824)
#define OFF_Q    (OFF_WO + 8388608)
#define OFF_K    (OFF_Q  + 16777216)
#define OFF_VT   (OFF_K  + 16777216)
#define OFF_O2   (OFF_VT + 16777216)

extern "C" void kernel_launch(void* const* d_in, const int* in_sizes, int n_in,
                              void* d_out, int out_size, void* d_ws, size_t ws_size,
                              hipStream_t stream) {
  (void)in_sizes; (void)n_in; (void)out_size; (void)ws_size;
  char* ws = (char*)d_ws;
  int*   flag = (int*)(ws + OFF_FLAG);
  float* fc   = (float*)(ws + OFF_FC);
  float* fs   = (float*)(ws + OFF_FS);
  short* Xb   = (short*)(ws + OFF_XB);
  short* Wqkv = (short*)(ws + OFF_WQKV);
  short* Wo   = (short*)(ws + OFF_WO);
  short* Qb   = (short*)(ws + OFF_Q);
  short* Kb   = (short*)(ws + OFF_K);
  short* Vtb  = (short*)(ws + OFF_VT);
  short* O2   = (short*)(ws + OFF_O2);

  k_cvt_fused<<<25600, 256, 0, stream>>>(d_in[0], d_in[4], d_in[5], d_in[6], d_in[7],
                                         d_in[1], d_in[2],
                                         (unsigned long long*)Xb,
                                         (unsigned long long*)Wqkv,
                                         (unsigned long long*)Wo, fc, fs, flag);

  k_gemm_qk2<<<dim3(32, 32), 256, 0, stream>>>(d_in[0], Xb,
                                               d_in[4], d_in[5], Wqkv,
                                               Qb, Kb, fc, fs, flag);

  k_gemm_v<<<dim3(16, 32), 256, 0, stream>>>(d_in[0], Xb, d_in[6], Wqkv, Vtb, flag);

  k_attn<<<512, 256, 0, stream>>>(Qb, Kb, Vtb, O2);

  k_gemm_wo<<<dim3(16, 32), 256, 0, stream>>>(O2, d_in[7], Wo, d_out, flag);
}

// Round 11
// 379.627 us; speedup vs baseline: 1.0254x; 1.0042x over previous
//
#include <hip/hip_runtime.h>

// MHA forward: x@Wq^T/Wk^T/Wv^T -> RoPE(q,k) -> softmax(qk^T/sqrt(hd))v -> @Wo^T
// B=2 H=16 S=2048 D=2048 HD=128. bf16 MFMA, fp32 accum.
// R16: two residual-overhead cuts on the locked R15 config:
//  (1) cvt grid-stride x8 (25600 -> 3200 blocks; bf16 mode had 24576 no-op
//      block launches).
//  (2) attn KVBLK 64 -> 128: halves iters (32->16) -> halves barrier +
//      vmcnt(0) drain count (the serial per-iter overhead at 2 waves/SIMD).
//      LDS 64KB (2 blk/CU, grid-matched). Swizzles re-derived bit-level:
//      fK(row)=q15 identity holds for kc*32 (bits>=5); K stage chunk =
//      kc0^(((i>>1)&1)<<2)^(((i>>2)&1)<<3), kc0=(lane&15)^krl; V rows now
//      16 chunks (stride 128 shorts), store swizzle ^(d&7), d&7=((i&1)<<2)|krl.
//      Bank check: 2 lanes/bank (free) on QK and PV reads. VGPR ~180 < 256.
// qk2/v/wo unchanged (R14/R15-verified).

#define DIMN 2048
#define SEQ  2048
#define NH   16
#define HDIM 128
#define NB   2
#define TOK  (NB*SEQ)          // 4096
#define QSCALE 0.08838834764831845f

typedef __attribute__((ext_vector_type(8)))  short bf16x8;
typedef __attribute__((ext_vector_type(4)))  float f32x4;
typedef __attribute__((ext_vector_type(16))) float f32x16;

__device__ __forceinline__ short f2bf(float f) {
  union { float f; unsigned u; } v; v.f = f;
  unsigned r = v.u + 0x7FFFu + ((v.u >> 16) & 1u);   // RNE
  return (short)(r >> 16);
}
__device__ __forceinline__ float bf2f(short b) {
  union { unsigned u; float f; } v; v.u = ((unsigned)(unsigned short)b) << 16;
  return v.f;
}
__device__ __forceinline__ unsigned packbf(float a, float b) {  // RNE pack
  union { float f; unsigned u; } x, y; x.f = a; y.f = b;
  unsigned ua = x.u + 0x7FFFu + ((x.u >> 16) & 1u);
  unsigned ub = y.u + 0x7FFFu + ((y.u >> 16) & 1u);
  return (ua >> 16) | (ub & 0xFFFF0000u);
}
__device__ __forceinline__ void async16(const void* g, void* l) {
  __builtin_amdgcn_global_load_lds(
      (const __attribute__((address_space(1))) unsigned*)g,
      (__attribute__((address_space(3))) unsigned*)l, 16, 0, 0);
}
// per-wave dtype detect from first 1KB of x: 1 = bf16 inputs
__device__ __forceinline__ int detect_bf16(const unsigned* x32) {
  const int lane = threadIdx.x & 63;
  int cnt = 0;
#pragma unroll
  for (int i = 0; i < 4; ++i) {
    unsigned w = x32[lane * 4 + i];
    unsigned e = (w >> 7) & 0xFFu;
    cnt += (e >= 90u && e <= 160u) ? 1 : 0;
  }
#pragma unroll
  for (int o = 1; o < 64; o <<= 1) cnt += __shfl_xor(cnt, o);
  return cnt > 180;
}

// ---- convert x + 4 weights (+freqs); grid-stride x8 (3200 blocks over the
// 25600 virtual-block space); copy iterations are no-ops in bf16 mode ----
__global__ void k_cvt_fused(const void* __restrict__ x,  const void* __restrict__ wq,
                            const void* __restrict__ wk, const void* __restrict__ wv,
                            const void* __restrict__ wo,
                            const void* __restrict__ cfr, const void* __restrict__ sfr,
                            unsigned long long* __restrict__ Xb,
                            unsigned long long* __restrict__ Wqkv,
                            unsigned long long* __restrict__ Wo,
                            float* __restrict__ fc, float* __restrict__ fs,
                            int* __restrict__ flagout) {
  const int fl = detect_bf16((const unsigned*)x);
  if (blockIdx.x == 0 && threadIdx.x == 0) *flagout = fl;
#pragma unroll 1
  for (int j = 0; j < 8; ++j) {
    const int blk = blockIdx.x * 8 + j;
    if (blk >= 24576) {                     // freqs: fp32 outputs (always)
      const int fb = blk - 24576;
      const void* src = (fb < 512) ? cfr : sfr;
      float* dst = (fb < 512) ? fc : fs;
      const int i = (fb & 511) * 256 + threadIdx.x;
      dst[i] = fl ? bf2f(((const short*)src)[i]) : ((const float*)src)[i];
      continue;
    }
    if (fl) continue;                       // bf16 inputs: GEMMs read d_in directly
    const void* src; unsigned long long* dst; int base;
    if      (blk <  8192) { src = x;  dst = Xb;             base = blk;          }
    else if (blk < 12288) { src = wq; dst = Wqkv;           base = blk - 8192;   }
    else if (blk < 16384) { src = wk; dst = Wqkv + 1048576; base = blk - 12288;  }
    else if (blk < 20480) { src = wv; dst = Wqkv + 2097152; base = blk - 16384;  }
    else                  { src = wo; dst = Wo;             base = blk - 20480;  }
    const int i = base * 256 + threadIdx.x;
    float4 v = ((const float4*)src)[i];
    dst[i] = (unsigned long long)(unsigned)packbf(v.x, v.y)
           | ((unsigned long long)(unsigned)packbf(v.z, v.w) << 32);
  }
}

// ---- Q+K GEMM: C[M=4096, N=4096] = X @ [Wq;Wk]^T, 2-phase 128^2 ----
// The 904-TF-measured structure restricted to the Q/K region.
// Grid 32x32 = 1024 blocks = exactly one round at 4 blocks/CU.
// Epilogue: wave-private LDS bounce + fused RoPE (Q scaled by QSCALE).
__global__ __launch_bounds__(256, 4)
void k_gemm_qk2(const void* __restrict__ xraw, const short* __restrict__ Xb,
                const void* __restrict__ wqraw, const void* __restrict__ wkraw,
                const short* __restrict__ Wcvt,
                short* __restrict__ Qb, short* __restrict__ Kb,
                const float* __restrict__ fc, const float* __restrict__ fs,
                const int* __restrict__ flagp) {
  __shared__ short As[128 * 64];
  __shared__ short Bs[128 * 64];
  const int tid = threadIdx.x, lane = tid & 63, wv = tid >> 6;
  const int lo = lane & 15, hi = lane >> 4;
  const int m_base = blockIdx.y * 128, n_base = blockIdx.x * 128;
  const int m0w = (wv >> 1) * 64, n0w = (wv & 1) * 64;
  const int rr = lane >> 3;
  const int gsw = (lane & 7) ^ (rr & 7);
  const int proj = n_base >> 11;              // 0=Q 1=K
  const int nloc = n_base & 2047;

  const int fl = *flagp;
  const short* Ap = fl ? (const short*)xraw : Xb;
  const short* Wp = fl ? (const short*)((proj == 0) ? wqraw : wkraw)
                       : (Wcvt + (size_t)proj * 4194304);

  f32x4 acc[4][4];
#pragma unroll
  for (int i = 0; i < 4; i++)
#pragma unroll
    for (int j = 0; j < 4; j++) acc[i][j] = (f32x4)0.0f;

  for (int k0 = 0; k0 < DIMN; k0 += 64) {
#pragma unroll
    for (int i = 0; i < 4; ++i) {
      const int c = wv * 4 + i;
      const int row = c * 8 + rr;
      async16(Ap + (size_t)(m_base + row) * DIMN + k0 + gsw * 8, &As[c * 512]);
      async16(Wp + (size_t)(nloc + row) * DIMN + k0 + gsw * 8, &Bs[c * 512]);
    }
    __syncthreads();
#pragma unroll
    for (int kb = 0; kb < 2; ++kb) {
      bf16x8 af[4], bfr[4];
      const int ph = ((kb * 4 + hi) ^ (lo & 7)) * 8;
#pragma unroll
      for (int mi = 0; mi < 4; mi++)
        af[mi] = *(const bf16x8*)&As[(m0w + mi * 16 + lo) * 64 + ph];
#pragma unroll
      for (int ni = 0; ni < 4; ni++)
        bfr[ni] = *(const bf16x8*)&Bs[(n0w + ni * 16 + lo) * 64 + ph];
#pragma unroll
      for (int mi = 0; mi < 4; mi++)
#pragma unroll
        for (int ni = 0; ni < 4; ni++)
          acc[mi][ni] = __builtin_amdgcn_mfma_f32_16x16x32_bf16(af[mi], bfr[ni], acc[mi][ni], 0, 0, 0);
    }
    __syncthreads();
  }

  // ---- epilogue: wave-private 64x64 bounce + fused RoPE ----
  short* Sw = (wv < 2) ? &As[wv * 4096] : &Bs[(wv - 2) * 4096];
  const int nl0 = nloc + n0w;
  const int h  = nl0 >> 7;
  const int d0 = nl0 & 127;
  const int b  = m_base >> 11;
  const int sb = (m_base + m0w) & 2047;

#pragma unroll
  for (int mi = 0; mi < 4; mi++)
#pragma unroll
    for (int ni = 0; ni < 4; ni++)
#pragma unroll
      for (int r = 0; r < 4; r++) {
        const int ml = mi * 16 + hi * 4 + r;
        const int nl = ni * 16 + lo;
        Sw[ml * 64 + (((nl >> 3) ^ (ml & 7)) * 8) + (nl & 7)] = f2bf(acc[mi][ni][r]);
      }
  const float qs = (proj == 0) ? QSCALE : 1.0f;
  short* Out = ((proj == 0) ? Qb : Kb) + (size_t)(b * NH + h) * SEQ * HDIM;
#pragma unroll
  for (int j = 0; j < 8; ++j) {
    const int rloc = (lane >> 3) + 8 * j;
    const int sg = sb + rloc;
    const int cc = lane & 7;
    const bf16x8 v = *(const bf16x8*)&Sw[rloc * 64 + ((cc ^ (rloc & 7)) * 8)];
    const int d2b = (d0 + cc * 8) >> 1;
    const float4 c4 = *(const float4*)&fc[sg * 64 + d2b];
    const float4 s4 = *(const float4*)&fs[sg * 64 + d2b];
    int4 o;
    { const float xr = bf2f(v[0]), xi = bf2f(v[1]);
      o.x = (int)packbf((xr * c4.x - xi * s4.x) * qs, (xr * s4.x + xi * c4.x) * qs); }
    { const float xr = bf2f(v[2]), xi = bf2f(v[3]);
      o.y = (int)packbf((xr * c4.y - xi * s4.y) * qs, (xr * s4.y + xi * c4.y) * qs); }
    { const float xr = bf2f(v[4]), xi = bf2f(v[5]);
      o.z = (int)packbf((xr * c4.z - xi * s4.z) * qs, (xr * s4.z + xi * c4.z) * qs); }
    { const float xr = bf2f(v[6]), xi = bf2f(v[7]);
      o.w = (int)packbf((xr * c4.w - xi * s4.w) * qs, (xr * s4.w + xi * c4.w) * qs); }
    *(int4*)&Out[(size_t)sg * HDIM + d0 + cc * 8] = o;
  }
}

// ---- V GEMM: Vt[b,h,d,s] from X @ Wv^T, 2-phase 128^2; runs right before
// attn so Vt is L2-resident when attn starts (R12-vs-R13 A/B evidence) ----
__global__ __launch_bounds__(256, 4)
void k_gemm_v(const void* __restrict__ xraw, const short* __restrict__ Xb,
              const void* __restrict__ wvraw, const short* __restrict__ Wcvt,
              short* __restrict__ Vtb, const int* __restrict__ flagp) {
  __shared__ short As[128 * 64];
  __shared__ short Bs[128 * 64];
  const int tid = threadIdx.x, lane = tid & 63, wv = tid >> 6;
  const int lo = lane & 15, hi = lane >> 4;
  const int m_base = blockIdx.y * 128;
  const int nloc = blockIdx.x * 128;          // within V's 2048 cols
  const int m0w = (wv >> 1) * 64, n0w = (wv & 1) * 64;
  const int rr = lane >> 3;
  const int gsw = (lane & 7) ^ (rr & 7);

  const int fl = *flagp;
  const short* Ap = fl ? (const short*)xraw : Xb;
  const short* Wp = fl ? (const short*)wvraw : (Wcvt + (size_t)2 * 4194304);

  f32x4 acc[4][4];
#pragma unroll
  for (int i = 0; i < 4; i++)
#pragma unroll
    for (int j = 0; j < 4; j++) acc[i][j] = (f32x4)0.0f;

  for (int k0 = 0; k0 < DIMN; k0 += 64) {
#pragma unroll
    for (int i = 0; i < 4; ++i) {
      const int c = wv * 4 + i;
      const int row = c * 8 + rr;
      async16(Ap + (size_t)(m_base + row) * DIMN + k0 + gsw * 8, &As[c * 512]);
      async16(Wp + (size_t)(nloc + row) * DIMN + k0 + gsw * 8, &Bs[c * 512]);
    }
    __syncthreads();
#pragma unroll
    for (int kb = 0; kb < 2; ++kb) {
      bf16x8 af[4], bfr[4];
      const int ph = ((kb * 4 + hi) ^ (lo & 7)) * 8;
#pragma unroll
      for (int mi = 0; mi < 4; mi++)
        af[mi] = *(const bf16x8*)&As[(m0w + mi * 16 + lo) * 64 + ph];
#pragma unroll
      for (int ni = 0; ni < 4; ni++)
        bfr[ni] = *(const bf16x8*)&Bs[(n0w + ni * 16 + lo) * 64 + ph];
#pragma unroll
      for (int mi = 0; mi < 4; mi++)
#pragma unroll
        for (int ni = 0; ni < 4; ni++)
          acc[mi][ni] = __builtin_amdgcn_mfma_f32_16x16x32_bf16(af[mi], bfr[ni], acc[mi][ni], 0, 0, 0);
    }
    __syncthreads();
  }

  // epilogue: transpose in wave-private bounce -> Vt[b,h,d,s]
  short* Sw = (wv < 2) ? &As[wv * 4096] : &Bs[(wv - 2) * 4096];
  const int nl0 = nloc + n0w;
  const int h  = nl0 >> 7;
  const int d0 = nl0 & 127;
  const int b  = m_base >> 11;
  const int sb = (m_base + m0w) & 2047;
#pragma unroll
  for (int mi = 0; mi < 4; mi++)
#pragma unroll
    for (int ni = 0; ni < 4; ni++)
#pragma unroll
      for (int r = 0; r < 4; r++) {
        const int dl = ni * 16 + lo;
        const int sl = mi * 16 + hi * 4 + r;
        Sw[dl * 64 + (((sl >> 3) ^ (dl & 7)) * 8) + (sl & 7)] = f2bf(acc[mi][ni][r]);
      }
  short* OutV = Vtb + (size_t)(b * NH + h) * HDIM * SEQ;
#pragma unroll
  for (int j = 0; j < 8; ++j) {
    const int dl = (lane >> 3) + 8 * j;
    const int cc = lane & 7;
    const int4 v = *(const int4*)&Sw[dl * 64 + ((cc ^ (dl & 7)) * 8)];
    *(int4*)&OutV[(size_t)(d0 + dl) * SEQ + sb + cc * 8] = v;
  }
}

// ---- Wo GEMM: out[M=4096, N=2048]; W selected per flag; bf16 path uses
// LDS-bounce dwordx4 epilogue, fp32 path scalar stores ----
__global__ __launch_bounds__(256, 4)
void k_gemm_wo(const short* __restrict__ A, const void* __restrict__ woraw,
               const short* __restrict__ Wcvt,
               void* __restrict__ out, const int* __restrict__ flagp) {
  __shared__ short As[128 * 64];
  __shared__ short Bs[128 * 64];
  const int tid = threadIdx.x, lane = tid & 63, wv = tid >> 6;
  const int lo = lane & 15, hi = lane >> 4;
  const int m_base = blockIdx.y * 128, n_base = blockIdx.x * 128;
  const int m0w = (wv >> 1) * 64, n0w = (wv & 1) * 64;
  const int rr = lane >> 3;
  const int gsw = (lane & 7) ^ (rr & 7);

  const int fl = *flagp;
  const short* Wp = fl ? (const short*)woraw : Wcvt;

  f32x4 acc[4][4];
#pragma unroll
  for (int i = 0; i < 4; i++)
#pragma unroll
    for (int j = 0; j < 4; j++) acc[i][j] = (f32x4)0.0f;

  for (int k0 = 0; k0 < DIMN; k0 += 64) {
#pragma unroll
    for (int i = 0; i < 4; ++i) {
      const int c = wv * 4 + i;
      const int row = c * 8 + rr;
      async16(A + (size_t)(m_base + row) * DIMN + k0 + gsw * 8, &As[c * 512]);
      async16(Wp + (size_t)(n_base + row) * DIMN + k0 + gsw * 8, &Bs[c * 512]);
    }
    __syncthreads();
#pragma unroll
    for (int kb = 0; kb < 2; ++kb) {
      bf16x8 af[4], bfr[4];
      const int ph = ((kb * 4 + hi) ^ (lo & 7)) * 8;
#pragma unroll
      for (int mi = 0; mi < 4; mi++)
        af[mi] = *(const bf16x8*)&As[(m0w + mi * 16 + lo) * 64 + ph];
#pragma unroll
      for (int ni = 0; ni < 4; ni++)
        bfr[ni] = *(const bf16x8*)&Bs[(n0w + ni * 16 + lo) * 64 + ph];
#pragma unroll
      for (int mi = 0; mi < 4; mi++)
#pragma unroll
        for (int ni = 0; ni < 4; ni++)
          acc[mi][ni] = __builtin_amdgcn_mfma_f32_16x16x32_bf16(af[mi], bfr[ni], acc[mi][ni], 0, 0, 0);
    }
    __syncthreads();
  }

  if (fl) {
    // bf16 output: wave-private LDS bounce -> dwordx4 stores
    short* Sw = (wv < 2) ? &As[wv * 4096] : &Bs[(wv - 2) * 4096];
#pragma unroll
    for (int mi = 0; mi < 4; mi++)
#pragma unroll
      for (int ni = 0; ni < 4; ni++)
#pragma unroll
        for (int r = 0; r < 4; r++) {
          const int ml = mi * 16 + hi * 4 + r;
          const int nl = ni * 16 + lo;
          Sw[ml * 64 + (((nl >> 3) ^ (ml & 7)) * 8) + (nl & 7)] = f2bf(acc[mi][ni][r]);
        }
    short* Out = (short*)out;
    const int mb = m_base + m0w, nb = n_base + n0w;
#pragma unroll
    for (int j = 0; j < 8; ++j) {
      const int rloc = (lane >> 3) + 8 * j;
      const int cc = lane & 7;
      const int4 v = *(const int4*)&Sw[rloc * 64 + ((cc ^ (rloc & 7)) * 8)];
      *(int4*)&Out[(size_t)(mb + rloc) * DIMN + nb + cc * 8] = v;
    }
  } else {
#pragma unroll
    for (int mi = 0; mi < 4; mi++)
#pragma unroll
      for (int ni = 0; ni < 4; ni++)
#pragma unroll
        for (int r = 0; r < 4; r++) {
          const int m = m_base + m0w + mi * 16 + hi * 4 + r;
          const int n = n_base + n0w + ni * 16 + lo;
          ((float*)out)[(size_t)m * DIMN + n] = acc[mi][ni][r];
        }
  }
}

// ---- Flash attention, 16x16x32 MFMA, 32 q-rows/wave (two 16-q tiles),
// KVBLK=128 (16 iters; halved barrier/drain count vs R15's 32) ----
//  K LDS [128][128], chunk c of row R at slot c^fK(R),
//    fK(R)=(R&3)|((R>>3)&1)<<2|((R>>4)&1)<<3; fK(Rb+h*4+kc*32)=q15 identity
//    holds for kc in 0..3 (kc*32 only touches bits>=5). Read slot=(kd*4+g)^q15.
//  V LDS [128][128] (row stride 128 shorts, 16 chunks), chunk c of row d at
//    slot c^(d&7); PV read slot=(kc*4+g)^(q15&7), kc 0..3.
//  Permuted-row QK (Rb=((q15>>2)<<3)+(q15&3)) -> P fully in-lane for PV.
//  Bank check (both reads): 8 lanes per 4-bank group = 2/bank = free.
__global__ __launch_bounds__(256, 2)
void k_attn(const short* __restrict__ Q, const short* __restrict__ K,
            const short* __restrict__ Vt, short* __restrict__ O2) {
  __shared__ short Ks[128 * 128];
  __shared__ short Vs[128 * 128];
  const int tid = threadIdx.x, lane = tid & 63, w = tid >> 6;
  const int q15 = lane & 15, g = lane >> 4;
  const int id = blockIdx.x;
  const int bh = id & 31;                 // id%8 = bh%8 -> head pinned to XCD
  const int qb = id >> 5;                 // 0..15
  const int q0 = qb * 128 + w * 32;       // wave owns 32 q-rows

  // Q fragments for both 16-q tiles: lane needs Q[q0+qt*16+q15][kd*32+g*8..+8]
  bf16x8 bq[2][4];
#pragma unroll
  for (int qt = 0; qt < 2; ++qt) {
    const short* Qrow = Q + ((size_t)bh * SEQ + q0 + qt * 16 + q15) * HDIM + g * 8;
#pragma unroll
    for (int kd = 0; kd < 4; ++kd) bq[qt][kd] = *(const bf16x8*)(Qrow + kd * 32);
  }

  f32x4 oacc[2][8];
#pragma unroll
  for (int qt = 0; qt < 2; ++qt)
#pragma unroll
    for (int dt = 0; dt < 8; ++dt) oacc[qt][dt] = (f32x4)0.0f;
  float lsA[2] = {0.0f, 0.0f};
  float lsB[2] = {0.0f, 0.0f};

  const short* Kbase = K  + (size_t)bh * SEQ * HDIM;
  const short* Vbase = Vt + (size_t)bh * HDIM * SEQ;

  // staging lane constants (4 waves cover the 128x128 K + 128x128 V tile;
  // 8 calls each, 4 rows/call, wave w owns rows [w*32, w*32+32))
  const int krl = lane >> 4;                              // row within quad
  const int kc0 = (lane & 15) ^ krl;
  // QK read: phys row base p16(q15)
  const int Rb = ((q15 >> 2) << 3) + (q15 & 3);

#pragma unroll 1
  for (int it = 0; it < SEQ / 128; ++it) {
    const int kv0 = it * 128;
#pragma unroll
    for (int i = 0; i < 8; ++i) {
      const int rbase = w * 32 + i * 4;
      // K: fK(rbase+krl) = krl | ((i>>1)&1)<<2 | ((i>>2)&1)<<3
      const int cK = kc0 ^ (((i >> 1) & 1) << 2) ^ (((i >> 2) & 1) << 3);
      async16(Kbase + (size_t)(kv0 + rbase + krl) * HDIM + cK * 8, &Ks[rbase * 128]);
      // V: d&7 = ((i&1)<<2) | krl
      const int cV = (lane & 15) ^ ((((i & 1) << 2)) | krl);
      async16(Vbase + (size_t)(rbase + krl) * SEQ + kv0 + cV * 8, &Vs[rbase * 128]);
    }
    asm volatile("s_waitcnt vmcnt(0)" ::: "memory");
    asm volatile("s_barrier" ::: "memory");

    // QK^T: sacc[qt][kc][h]; each ak read feeds both q-tiles
    f32x4 sacc[2][4][2];
#pragma unroll
    for (int qt = 0; qt < 2; ++qt)
#pragma unroll
      for (int kc = 0; kc < 4; ++kc)
#pragma unroll
        for (int h = 0; h < 2; ++h) sacc[qt][kc][h] = (f32x4)0.0f;
    __builtin_amdgcn_s_setprio(1);
#pragma unroll
    for (int kd = 0; kd < 4; ++kd) {
      const int sl = ((kd * 4 + g) ^ q15) * 8;
#pragma unroll
      for (int kc = 0; kc < 4; ++kc)
#pragma unroll
        for (int h = 0; h < 2; ++h) {
          const bf16x8 ak = *(const bf16x8*)&Ks[(Rb + h * 4 + kc * 32) * 128 + sl];
          sacc[0][kc][h] = __builtin_amdgcn_mfma_f32_16x16x32_bf16(ak, bq[0][kd], sacc[0][kc][h], 0, 0, 0);
          sacc[1][kc][h] = __builtin_amdgcn_mfma_f32_16x16x32_bf16(ak, bq[1][kd], sacc[1][kc][h], 0, 0, 0);
        }
    }
    __builtin_amdgcn_s_setprio(0);

    // exp + partial sums + bf16 pack (all in-lane; e = h*4+r ordering)
    bf16x8 bp[2][4];
#pragma unroll
    for (int qt = 0; qt < 2; ++qt)
#pragma unroll
      for (int kc = 0; kc < 4; ++kc) {
        const float a0 = __expf(sacc[qt][kc][0][0]), a1 = __expf(sacc[qt][kc][0][1]);
        const float a2 = __expf(sacc[qt][kc][0][2]), a3 = __expf(sacc[qt][kc][0][3]);
        const float b0 = __expf(sacc[qt][kc][1][0]), b1 = __expf(sacc[qt][kc][1][1]);
        const float b2 = __expf(sacc[qt][kc][1][2]), b3 = __expf(sacc[qt][kc][1][3]);
        lsA[qt] += (a0 + a1) + (a2 + a3);
        lsB[qt] += (b0 + b1) + (b2 + b3);
        unsigned w0, w1, w2, w3;
        asm("v_cvt_pk_bf16_f32 %0, %1, %2" : "=v"(w0) : "v"(a0), "v"(a1));
        asm("v_cvt_pk_bf16_f32 %0, %1, %2" : "=v"(w1) : "v"(a2), "v"(a3));
        asm("v_cvt_pk_bf16_f32 %0, %1, %2" : "=v"(w2) : "v"(b0), "v"(b1));
        asm("v_cvt_pk_bf16_f32 %0, %1, %2" : "=v"(w3) : "v"(b2), "v"(b3));
        union { int4 i4; bf16x8 b; } pu;
        pu.i4.x = (int)w0; pu.i4.y = (int)w1;   // kv offsets e=0..3 (h=0)
        pu.i4.z = (int)w2; pu.i4.w = (int)w3;   // kv offsets e=4..7 (h=1)
        bp[qt][kc] = pu.b;
      }

    // PV: each av read feeds both q-tiles
    __builtin_amdgcn_s_setprio(1);
#pragma unroll
    for (int kc = 0; kc < 4; ++kc) {
      const int slv = ((kc * 4 + g) ^ (q15 & 7)) * 8;
#pragma unroll
      for (int dt = 0; dt < 8; ++dt) {
        const bf16x8 av = *(const bf16x8*)&Vs[(dt * 16 + q15) * 128 + slv];
        oacc[0][dt] = __builtin_amdgcn_mfma_f32_16x16x32_bf16(av, bp[0][kc], oacc[0][dt], 0, 0, 0);
        oacc[1][dt] = __builtin_amdgcn_mfma_f32_16x16x32_bf16(av, bp[1][kc], oacc[1][dt], 0, 0, 0);
      }
    }
    __builtin_amdgcn_s_setprio(0);
    asm volatile("s_barrier" ::: "memory");   // reads done before next stage
  }

  // column sums l(q) per q-tile: reduce across the 4 g-lanes of column q15
  const int b = bh >> 4, h = bh & 15;
#pragma unroll
  for (int qt = 0; qt < 2; ++qt) {
    float ls = lsA[qt] + lsB[qt];
    ls += __shfl_xor(ls, 16);
    ls += __shfl_xor(ls, 32);
    const float inv = 1.0f / ls;
    // lane holds O[d = dt*16 + g*4 + r][q15] -> O2[b, s=q0+qt*16+q15, h*128+d]
    short* ob = O2 + ((size_t)(b * SEQ + q0 + qt * 16 + q15) * DIMN + h * HDIM + g * 4);
#pragma unroll
    for (int dt = 0; dt < 8; ++dt) {
      const unsigned w0 = packbf(oacc[qt][dt][0] * inv, oacc[qt][dt][1] * inv);
      const unsigned w1 = packbf(oacc[qt][dt][2] * inv, oacc[qt][dt][3] * inv);
      *(unsigned long long*)&ob[dt * 16] = (unsigned long long)w0 | ((unsigned long long)w1 << 32);
    }
  }
}

// ---- workspace layout (bytes) ----
#define OFF_FLAG 0
#define OFF_FC   1024
#define OFF_FS   (OFF_FC + 524288)
#define OFF_XB   (OFF_FS + 524288)
#define OFF_WQKV (OFF_XB + 16777216)
#define OFF_WO   (OFF_WQKV + 25165824)
#define OFF_Q    (OFF_WO + 8388608)
#define OFF_K    (OFF_Q  + 16777216)
#define OFF_VT   (OFF_K  + 16777216)
#define OFF_O2   (OFF_VT + 16777216)

extern "C" void kernel_launch(void* const* d_in, const int* in_sizes, int n_in,
                              void* d_out, int out_size, void* d_ws, size_t ws_size,
                              hipStream_t stream) {
  (void)in_sizes; (void)n_in; (void)out_size; (void)ws_size;
  char* ws = (char*)d_ws;
  int*   flag = (int*)(ws + OFF_FLAG);
  float* fc   = (float*)(ws + OFF_FC);
  float* fs   = (float*)(ws + OFF_FS);
  short* Xb   = (short*)(ws + OFF_XB);
  short* Wqkv = (short*)(ws + OFF_WQKV);
  short* Wo   = (short*)(ws + OFF_WO);
  short* Qb   = (short*)(ws + OFF_Q);
  short* Kb   = (short*)(ws + OFF_K);
  short* Vtb  = (short*)(ws + OFF_VT);
  short* O2   = (short*)(ws + OFF_O2);

  k_cvt_fused<<<3200, 256, 0, stream>>>(d_in[0], d_in[4], d_in[5], d_in[6], d_in[7],
                                        d_in[1], d_in[2],
                                        (unsigned long long*)Xb,
                                        (unsigned long long*)Wqkv,
                                        (unsigned long long*)Wo, fc, fs, flag);

  k_gemm_qk2<<<dim3(32, 32), 256, 0, stream>>>(d_in[0], Xb,
                                               d_in[4], d_in[5], Wqkv,
                                               Qb, Kb, fc, fs, flag);

  k_gemm_v<<<dim3(16, 32), 256, 0, stream>>>(d_in[0], Xb, d_in[6], Wqkv, Vtb, flag);

  k_attn<<<512, 256, 0, stream>>>(Qb, Kb, Vtb, O2);

  k_gemm_wo<<<dim3(16, 32), 256, 0, stream>>>(O2, d_in[7], Wo, d_out, flag);
}